// Round 8
// baseline (3497.390 us; speedup 1.0000x reference)
//
#include <hip/hip_runtime.h>
#include <hip/hip_bf16.h>

#define BB 512
#define SS 256
#define HH 256
#define DD 64
#define TT 50
#define GG 1024   // 4*H
#define INW 129

typedef _Float16 h4 __attribute__((ext_vector_type(4)));
typedef _Float16 h8 __attribute__((ext_vector_type(8)));
typedef __fp16 hf2 __attribute__((ext_vector_type(2)));   // builtin-facing f16 pair
typedef float f32x4 __attribute__((ext_vector_type(4)));
typedef unsigned int u32;

__device__ inline float sigf(float x) { return 1.f / (1.f + __expf(-x)); }
__device__ inline float tanhf_(float x) { return 1.f - 2.f / (__expf(2.f * x) + 1.f); }

__device__ inline u32 pkrtz(float a, float b) {
    hf2 h = __builtin_amdgcn_cvt_pkrtz(a, b);
    return __builtin_bit_cast(u32, h);
}

// ============ prep: unchanged (validated) ============
__global__ __launch_bounds__(256) void prep_kernel(
    const float* __restrict__ W_hh, const float* __restrict__ W_ih,
    const float* __restrict__ Wd1, const float* __restrict__ Wd2,
    h4* __restrict__ BhhV4, h4* __restrict__ BhhL4, h4* __restrict__ BhhS4,
    _Float16* __restrict__ Bih, h4* __restrict__ A1f4, h4* __restrict__ A2f4)
{
    int idx = blockIdx.x * 256 + threadIdx.x;
    if (idx < 65536) {
        int eh = idx & 1;
        int l = (idx >> 1) & 63;
        int ks = (idx >> 7) & 7;
        int s = (idx >> 10) & 7;
        int w = (idx >> 13) & 7;
        int g = s & 3, jt = s >> 2;
        int n = g * 256 + w * 32 + jt * 16 + (l & 15);
        int k = 32 * ks + 8 * (l >> 4) + 4 * eh;
        float4 v = *(const float4*)(W_hh + (size_t)n * HH + k);
        h4 o; o[0] = (_Float16)v.x; o[1] = (_Float16)v.y; o[2] = (_Float16)v.z; o[3] = (_Float16)v.w;
        if (ks < 4)      BhhV4[(((w * 8 + s) * 4 + ks) * 64 + l) * 2 + eh] = o;
        else if (ks < 6) BhhL4[(((w * 8 + s) * 2 + (ks - 4)) * 64 + l) * 2 + eh] = o;
        else             BhhS4[(((w * 8 + s) * 2 + (ks - 6)) * 64 + l) * 2 + eh] = o;
    } else if (idx < 106496) {
        int fj = idx - 65536;
        int eh = fj & 1;
        int l = (fj >> 1) & 63;
        int si = fj >> 7;              // [0,320) = ntile*5 + ks
        int ks = si % 5;
        int ntile = si / 5;
        int n = ntile * 16 + (l & 15);
        int k = 32 * ks + 8 * (l >> 4) + 4 * eh;
        h4 o;
#pragma unroll
        for (int i = 0; i < 4; i++) {
            int kk = k + i;
            o[i] = (_Float16)((kk < INW) ? W_ih[(size_t)n * INW + kk] : 0.f);
        }
        *(h4*)(Bih + (size_t)fj * 4) = o;
    } else if (idx < 110592) {
        int fj = idx - 106496;         // A1f: 32 slots * 64 lanes * 2
        int eh = fj & 1;
        int l = (fj >> 1) & 63;
        int slot = fj >> 7;            // t*2+ks
        int ks = slot & 1, t = slot >> 1;
        int row = 16 * t + (l & 15);
        int k = 32 * ks + 8 * (l >> 4) + 4 * eh;
        h4 o;
#pragma unroll
        for (int i = 0; i < 4; i++) o[i] = (_Float16)Wd1[(size_t)row * DD + k + i];
        A1f4[fj] = o;
    } else if (idx < 114688) {
        int fj = idx - 110592;         // A2f: 32 slots * 64 lanes * 2
        int eh = fj & 1;
        int l = (fj >> 1) & 63;
        int slot = fj >> 7;            // t2*8+ks
        int ks = slot & 7, t2 = slot >> 3;
        int row = 16 * t2 + (l & 15);
        int k = 32 * ks + 8 * (l >> 4) + 4 * eh;
        h4 o;
#pragma unroll
        for (int i = 0; i < 4; i++) o[i] = (_Float16)Wd2[(size_t)row * HH + k + i];
        A2f4[fj] = o;
    }
}

// ============ xw GEMM (MFMA): validated, unchanged ============
__global__ __launch_bounds__(256) void xw_kernel(
    const float* __restrict__ x, const _Float16* __restrict__ Bih,
    const float* __restrict__ b_ih, const float* __restrict__ b_hh,
    h4* __restrict__ xwf)
{
    __shared__ __align__(16) _Float16 ash[4][5][64][8];   // 20 KB, A-frag layout
    int tid = threadIdx.x;
    int w4 = tid >> 6, l = tid & 63;
    int bx = blockIdx.x;
    int t = bx >> 3, Bb = bx & 7;           // 64 batch-rows: b = Bb*64 + rr

    for (int i = tid; i < 64 * 160; i += 256) {
        int rr = i / 160, kk = i % 160;
        float v = (kk < INW) ? x[((size_t)(Bb * 64 + rr) * SS + t) * INW + kk] : 0.f;
        ash[rr >> 4][kk >> 5][(((kk & 31) >> 3) << 4) + (rr & 15)][kk & 7] = (_Float16)v;
    }
    __syncthreads();

    h8 A[4][5];
#pragma unroll
    for (int ms = 0; ms < 4; ms++)
#pragma unroll
        for (int ks = 0; ks < 5; ks++)
            A[ms][ks] = *(h8*)&ash[ms][ks][l][0];

    const h8* Bih8 = (const h8*)Bih;
    for (int nt16 = 0; nt16 < 16; nt16++) {
        int ntile = w4 * 16 + nt16;
        h8 Bv[5];
#pragma unroll
        for (int ks = 0; ks < 5; ks++) Bv[ks] = Bih8[(ntile * 5 + ks) * 64 + l];
        int nb = ntile * 16 + (l & 15);
        float bias = b_ih[nb] + b_hh[nb];
        f32x4 acc[4];
#pragma unroll
        for (int ms = 0; ms < 4; ms++) acc[ms] = (f32x4){0.f, 0.f, 0.f, 0.f};
#pragma unroll
        for (int ks = 0; ks < 5; ks++)
#pragma unroll
            for (int ms = 0; ms < 4; ms++)
                acc[ms] = __builtin_amdgcn_mfma_f32_16x16x32_f16(A[ms][ks], Bv[ks], acc[ms], 0, 0, 0);
        int slot = ((ntile & 15) >> 1) * 8 + (ntile & 1) * 4 + (ntile >> 4);
#pragma unroll
        for (int ms = 0; ms < 4; ms++) {
            int bg = Bb * 4 + ms;
            h4 o;
#pragma unroll
            for (int r = 0; r < 4; r++) o[r] = (_Float16)(acc[ms][r] + bias);
            xwf[(((size_t)bg * SS + t) * 64 + slot) * 64 + l] = o;
        }
    }
}

// ============ LSTM: exact round-5 kernel (measured 1108 us) ============
__global__ __launch_bounds__(512, 2) void lstm_kernel(
    const h8* __restrict__ BhhV, const h8* __restrict__ BhhL, const h8* __restrict__ BhhS,
    const h4* __restrict__ xwf, const int* __restrict__ lengths, float* __restrict__ pooled)
{
    __shared__ __align__(16) _Float16 Wlds[65536];        // 128 KB: ks4-5 weight fragments
    __shared__ __align__(16) _Float16 hbuf[2][8][64][8];  // 16 KB double-buffered A-frag h
    int tid = threadIdx.x;
    int w = tid >> 6, l = tid & 63;
    int bg = blockIdx.x;

    {   // copy ks4-5 weights into LDS (linear, 128 KB)
        const uint4* src = (const uint4*)BhhL;
        uint4* dst = (uint4*)Wlds;
#pragma unroll
        for (int i = 0; i < 16; i++) dst[i * 512 + tid] = src[i * 512 + tid];
    }

    h8 Wv[8][4];
#pragma unroll
    for (int s = 0; s < 8; s++)
#pragma unroll
        for (int ks = 0; ks < 4; ks++)
            Wv[s][ks] = BhhV[((w * 8 + s) * 4 + ks) * 64 + l];

    int len_[4];
    float c_[2][4], pa[2][4];
#pragma unroll
    for (int r = 0; r < 4; r++) {
        int b = 4 * (l >> 4) + r;
        len_[r] = lengths[bg * 16 + b];
#pragma unroll
        for (int jt = 0; jt < 2; jt++) { c_[jt][r] = 0.f; pa[jt][r] = 0.f; }
    }

    {   // zero h buffers (h0 = 0): 1024 uint4, 2 per thread
        uint4* hz = (uint4*)hbuf;
        hz[tid] = make_uint4(0, 0, 0, 0);
        hz[512 + tid] = make_uint4(0, 0, 0, 0);
    }
    __syncthreads();

    int cur = 0;
    for (int t = 0; t < SS; t++) {
        const h4* xpb = xwf + (((size_t)bg * SS + t) * 64 + w * 8) * 64 + l;
        int zoff = 0;
        asm volatile("" : "+v"(zoff));            // block LICM: force per-step re-load of streamed weights
        const h8* bS = BhhS + zoff;
#pragma unroll
        for (int jt = 0; jt < 2; jt++) {
            h4 xv[4];
#pragma unroll
            for (int g = 0; g < 4; g++) xv[g] = xpb[(jt * 4 + g) * 64];
            h8 Ws[4];
#pragma unroll
            for (int g = 0; g < 4; g++) Ws[g] = bS[((w * 8 + jt * 4 + g) * 2 + 0) * 64 + l];
            f32x4 acc[4];
#pragma unroll
            for (int g = 0; g < 4; g++) acc[g] = (f32x4){0.f, 0.f, 0.f, 0.f};
            // ks 0-3 from VGPR/AGPR weights
#pragma unroll
            for (int ks = 0; ks < 4; ks++) {
                h8 A = *(const h8*)&hbuf[cur][ks][l][0];
#pragma unroll
                for (int g = 0; g < 4; g++)
                    acc[g] = __builtin_amdgcn_mfma_f32_16x16x32_f16(A, Wv[jt * 4 + g][ks], acc[g], 0, 0, 0);
            }
            // ks 6 (streamed, landed)
            {
                h8 A = *(const h8*)&hbuf[cur][6][l][0];
#pragma unroll
                for (int g = 0; g < 4; g++)
                    acc[g] = __builtin_amdgcn_mfma_f32_16x16x32_f16(A, Ws[g], acc[g], 0, 0, 0);
            }
            // reissue stream for ks 7 into same regs
#pragma unroll
            for (int g = 0; g < 4; g++) Ws[g] = bS[((w * 8 + jt * 4 + g) * 2 + 1) * 64 + l];
            // ks 4-5 from LDS
#pragma unroll
            for (int ks = 4; ks < 6; ks++) {
                h8 A = *(const h8*)&hbuf[cur][ks][l][0];
#pragma unroll
                for (int g = 0; g < 4; g++) {
                    h8 Bw = *(const h8*)&Wlds[(((w * 8 + jt * 4 + g) * 2 + (ks - 4)) * 64 + l) * 8];
                    acc[g] = __builtin_amdgcn_mfma_f32_16x16x32_f16(A, Bw, acc[g], 0, 0, 0);
                }
            }
            // ks 7
            {
                h8 A = *(const h8*)&hbuf[cur][7][l][0];
#pragma unroll
                for (int g = 0; g < 4; g++)
                    acc[g] = __builtin_amdgcn_mfma_f32_16x16x32_f16(A, Ws[g], acc[g], 0, 0, 0);
            }
            // gates + h update
#pragma unroll
            for (int r = 0; r < 4; r++) {
                float gi = acc[0][r] + (float)xv[0][r];
                float gf = acc[1][r] + (float)xv[1][r];
                float gg = acc[2][r] + (float)xv[2][r];
                float go = acc[3][r] + (float)xv[3][r];
                float cc = sigf(gf) * c_[jt][r] + sigf(gi) * tanhf_(gg);
                c_[jt][r] = cc;
                float hh = sigf(go) * tanhf_(cc);
                if (t < len_[r]) pa[jt][r] += hh;
                int b = 4 * (l >> 4) + r;
                int j = w * 32 + jt * 16 + (l & 15);
                hbuf[cur ^ 1][j >> 5][(((j & 31) >> 3) << 4) + b][j & 7] = (_Float16)hh;
            }
        }
        __syncthreads();
        cur ^= 1;
    }

#pragma unroll
    for (int jt = 0; jt < 2; jt++)
#pragma unroll
        for (int r = 0; r < 4; r++) {
            int b = 4 * (l >> 4) + r;
            int j = w * 32 + jt * 16 + (l & 15);
            pooled[(size_t)(bg * 16 + b) * HH + j] = pa[jt][r] / (float)len_[r];
        }
}

// ============ head: unchanged ============
__global__ __launch_bounds__(256) void head_kernel(
    const float* __restrict__ pooled, const float* __restrict__ Wp1,
    const float* __restrict__ bp1, const float* __restrict__ Wp2,
    const float* __restrict__ bp2, float* __restrict__ y0ws)
{
    __shared__ __align__(16) float psh[HH];
    __shared__ __align__(16) float rsh[HH];
    int tid = threadIdx.x, b = blockIdx.x;
    psh[tid] = pooled[(size_t)b * HH + tid];
    __syncthreads();
    float a = bp1[tid];
    const float* wr = Wp1 + (size_t)tid * HH;
#pragma unroll 8
    for (int k = 0; k < HH; k += 4) {
        float4 w = *(const float4*)(wr + k);
        a += psh[k] * w.x + psh[k + 1] * w.y + psh[k + 2] * w.z + psh[k + 3] * w.w;
    }
    rsh[tid] = fmaxf(a, 0.f);
    __syncthreads();
    if (tid < DD) {
        float acc = bp2[tid];
        const float* w2 = Wp2 + (size_t)tid * HH;
#pragma unroll 8
        for (int h = 0; h < HH; h += 4) {
            float4 w = *(const float4*)(w2 + h);
            acc += rsh[h] * w.x + rsh[h + 1] * w.y + rsh[h + 2] * w.z + rsh[h + 3] * w.w;
        }
        y0ws[(size_t)b * DD + tid] = acc;
    }
}

// ============ ODE v5: single-wave per 16 batches, zero cross-wave sync ============
// One wave (64 lanes) owns 16 batches end-to-end: all 64 MFMAs per eval in-wave.
// Weights A1 (32 h8) + A2 (32 h8) = 256 regs -> AGPRs (unified file, 1 wave/SIMD -> 512 budget).
// Bias folded into MFMA C-seed. LDS turnarounds are wave-internal (syncthreads = bare waitcnt).
// hX row stride 264 halfs / kX stride 80: 16B-aligned, rows not bank-aligned (r7's 1.67e8-conflict fix).
__global__ __launch_bounds__(64, 1) void ode_kernel(
    const float* __restrict__ y0ws, const h8* __restrict__ A1f,
    const float* __restrict__ bd1, const h8* __restrict__ A2f,
    const float* __restrict__ bd2, const float* __restrict__ ltime,
    const float* __restrict__ lfeat, const float* __restrict__ lmask,
    float* __restrict__ pred, float* __restrict__ losso)
{
    __shared__ __align__(16) _Float16 hX[16 * 264];   // 8448 B, row stride 264
    __shared__ __align__(16) _Float16 kX[16 * 80];    // 2560 B, row stride 80
    int l = threadIdx.x;
    int q = l >> 4, bb = l & 15;
    int bg = blockIdx.x;
    int b = bg * 16 + bb;

    // weights resident in registers (AGPR-backed)
    h8 A1[16][2];
#pragma unroll
    for (int tt = 0; tt < 16; tt++)
#pragma unroll
        for (int ks = 0; ks < 2; ks++)
            A1[tt][ks] = A1f[(tt * 2 + ks) * 64 + l];
    h8 A2[4][8];
#pragma unroll
    for (int t2 = 0; t2 < 4; t2++)
#pragma unroll
        for (int ks = 0; ks < 8; ks++)
            A2[t2][ks] = A2f[(t2 * 8 + ks) * 64 + l];

    // bias as f32x4 C-seeds (C row = 16*tile + 4q + r, col = bb)
    f32x4 BD1[16], BD2[4];
#pragma unroll
    for (int tt = 0; tt < 16; tt++)
#pragma unroll
        for (int r = 0; r < 4; r++) BD1[tt][r] = bd1[16 * tt + 4 * q + r];
#pragma unroll
    for (int t2 = 0; t2 < 4; t2++)
#pragma unroll
        for (int r = 0; r < 4; r++) BD2[t2][r] = bd2[16 * t2 + 4 * q + r];

    // y state: lane (bb,q) holds k = 32*ks2 + 8q + e (B-frag layout)
    float y[16], kp[16], ksum[16];
#pragma unroll
    for (int ks2 = 0; ks2 < 2; ks2++) {
        float4 y0a = *(const float4*)&y0ws[(size_t)b * DD + 32 * ks2 + 8 * q];
        float4 y0b = *(const float4*)&y0ws[(size_t)b * DD + 32 * ks2 + 8 * q + 4];
        y[ks2 * 8 + 0] = y0a.x; y[ks2 * 8 + 1] = y0a.y; y[ks2 * 8 + 2] = y0a.z; y[ks2 * 8 + 3] = y0a.w;
        y[ks2 * 8 + 4] = y0b.x; y[ks2 * 8 + 5] = y0b.y; y[ks2 * 8 + 6] = y0b.z; y[ks2 * 8 + 7] = y0b.w;
#pragma unroll
        for (int e = 0; e < 8; e++) kp[ks2 * 8 + e] = 0.f;
    }

    // pred/loss at ti=0 (each lane writes its 16 lane-local dims)
#pragma unroll
    for (int ks2 = 0; ks2 < 2; ks2++) {
        size_t idx = ((size_t)b * TT + 0) * DD + 32 * ks2 + 8 * q;
#pragma unroll
        for (int h4i = 0; h4i < 2; h4i++) {
            float4 p;
            p.x = y[ks2 * 8 + 4 * h4i + 0]; p.y = y[ks2 * 8 + 4 * h4i + 1];
            p.z = y[ks2 * 8 + 4 * h4i + 2]; p.w = y[ks2 * 8 + 4 * h4i + 3];
            *(float4*)&pred[idx + 4 * h4i] = p;
            float4 lf = *(const float4*)&lfeat[idx + 4 * h4i];
            float4 lm = *(const float4*)&lmask[idx + 4 * h4i];
            float4 lo;
            lo.x = (p.x - lf.x) * (p.x - lf.x) * (1.f - lm.x);
            lo.y = (p.y - lf.y) * (p.y - lf.y) * (1.f - lm.y);
            lo.z = (p.z - lf.z) * (p.z - lf.z) * (1.f - lm.z);
            lo.w = (p.w - lf.w) * (p.w - lf.w) * (1.f - lm.w);
            *(float4*)&losso[idx + 4 * h4i] = lo;
        }
    }

    for (int iv = 0; iv < TT - 1; iv++) {
        float t0 = ltime[(size_t)b * TT + iv], t1 = ltime[(size_t)b * TT + iv + 1];
        float dt = (t1 - t0) * 0.125f;
        for (int ss = 0; ss < 8; ss++) {
#pragma unroll
            for (int i = 0; i < 16; i++) ksum[i] = 0.f;
            const float AE[4] = {0.f, 0.5f, 0.5f, 1.f};
            const float WE[4] = {1.f, 2.f, 2.f, 1.f};
#pragma unroll
            for (int e = 0; e < 4; e++) {
                float adt = AE[e] * dt;
                // B1 = pack(y + adt*kp), lane-local
                h8 B1[2];
#pragma unroll
                for (int ks2 = 0; ks2 < 2; ks2++) {
                    uint4 u;
                    u.x = pkrtz(y[ks2 * 8 + 0] + adt * kp[ks2 * 8 + 0], y[ks2 * 8 + 1] + adt * kp[ks2 * 8 + 1]);
                    u.y = pkrtz(y[ks2 * 8 + 2] + adt * kp[ks2 * 8 + 2], y[ks2 * 8 + 3] + adt * kp[ks2 * 8 + 3]);
                    u.z = pkrtz(y[ks2 * 8 + 4] + adt * kp[ks2 * 8 + 4], y[ks2 * 8 + 5] + adt * kp[ks2 * 8 + 5]);
                    u.w = pkrtz(y[ks2 * 8 + 6] + adt * kp[ks2 * 8 + 6], y[ks2 * 8 + 7] + adt * kp[ks2 * 8 + 7]);
                    B1[ks2] = __builtin_bit_cast(h8, u);
                }
                // GEMV1: 16 tiles x 2 ks, bias-seeded; relu+pack+store per tile
#pragma unroll
                for (int tt = 0; tt < 16; tt++) {
                    f32x4 C = BD1[tt];
                    C = __builtin_amdgcn_mfma_f32_16x16x32_f16(A1[tt][0], B1[0], C, 0, 0, 0);
                    C = __builtin_amdgcn_mfma_f32_16x16x32_f16(A1[tt][1], B1[1], C, 0, 0, 0);
                    u32 p0 = pkrtz(fmaxf(C[0], 0.f), fmaxf(C[1], 0.f));
                    u32 p1 = pkrtz(fmaxf(C[2], 0.f), fmaxf(C[3], 0.f));
                    *(uint2*)&hX[bb * 264 + 16 * tt + 4 * q] = make_uint2(p0, p1);
                }
                __syncthreads();   // 1-wave block: bare waitcnt, no partner waves
                // GEMV2: 4 tiles x 8 ks, bias-seeded
                f32x4 C2[4];
#pragma unroll
                for (int t2 = 0; t2 < 4; t2++) C2[t2] = BD2[t2];
#pragma unroll
                for (int ksi = 0; ksi < 8; ksi++) {
                    h8 B2 = *(const h8*)&hX[bb * 264 + 32 * ksi + 8 * q];
#pragma unroll
                    for (int t2 = 0; t2 < 4; t2++)
                        C2[t2] = __builtin_amdgcn_mfma_f32_16x16x32_f16(A2[t2][ksi], B2, C2[t2], 0, 0, 0);
                }
#pragma unroll
                for (int t2 = 0; t2 < 4; t2++) {
                    u32 p0 = pkrtz(C2[t2][0], C2[t2][1]);
                    u32 p1 = pkrtz(C2[t2][2], C2[t2][3]);
                    *(uint2*)&kX[bb * 80 + 16 * t2 + 4 * q] = make_uint2(p0, p1);
                }
                __syncthreads();
                // read k back in B-frag layout; update kp/ksum
#pragma unroll
                for (int ks2 = 0; ks2 < 2; ks2++) {
                    h8 kf = *(const h8*)&kX[bb * 80 + 32 * ks2 + 8 * q];
#pragma unroll
                    for (int e2 = 0; e2 < 8; e2++) {
                        float kv = (float)kf[e2];
                        kp[ks2 * 8 + e2] = kv;
                        ksum[ks2 * 8 + e2] += WE[e] * kv;
                    }
                }
                __syncthreads();   // protect hX/kX from next stage's overwrites
            }
#pragma unroll
            for (int i = 0; i < 16; i++) y[i] += dt * (1.f / 6.f) * ksum[i];
        }
        // pred/loss at ti=iv+1
#pragma unroll
        for (int ks2 = 0; ks2 < 2; ks2++) {
            size_t idx = ((size_t)b * TT + iv + 1) * DD + 32 * ks2 + 8 * q;
#pragma unroll
            for (int h4i = 0; h4i < 2; h4i++) {
                float4 p;
                p.x = y[ks2 * 8 + 4 * h4i + 0]; p.y = y[ks2 * 8 + 4 * h4i + 1];
                p.z = y[ks2 * 8 + 4 * h4i + 2]; p.w = y[ks2 * 8 + 4 * h4i + 3];
                *(float4*)&pred[idx + 4 * h4i] = p;
                float4 lf = *(const float4*)&lfeat[idx + 4 * h4i];
                float4 lm = *(const float4*)&lmask[idx + 4 * h4i];
                float4 lo;
                lo.x = (p.x - lf.x) * (p.x - lf.x) * (1.f - lm.x);
                lo.y = (p.y - lf.y) * (p.y - lf.y) * (1.f - lm.y);
                lo.z = (p.z - lf.z) * (p.z - lf.z) * (1.f - lm.z);
                lo.w = (p.w - lf.w) * (p.w - lf.w) * (1.f - lm.w);
                *(float4*)&losso[idx + 4 * h4i] = lo;
            }
        }
    }
}

extern "C" void kernel_launch(void* const* d_in, const int* in_sizes, int n_in,
                              void* d_out, int out_size, void* d_ws, size_t ws_size,
                              hipStream_t stream)
{
    const float* x      = (const float*)d_in[0];
    const int* lengths  = (const int*)d_in[1];
    const float* lfeat  = (const float*)d_in[2];
    const float* ltime  = (const float*)d_in[3];
    const float* lmask  = (const float*)d_in[4];
    const float* W_ih   = (const float*)d_in[5];
    const float* W_hh   = (const float*)d_in[6];
    const float* b_ih   = (const float*)d_in[7];
    const float* b_hh   = (const float*)d_in[8];
    const float* Wp1    = (const float*)d_in[9];
    const float* bp1    = (const float*)d_in[10];
    const float* Wp2    = (const float*)d_in[11];
    const float* bp2    = (const float*)d_in[12];
    const float* Wd1    = (const float*)d_in[13];
    const float* bd1    = (const float*)d_in[14];
    const float* Wd2    = (const float*)d_in[15];
    const float* bd2    = (const float*)d_in[16];

    float* pred  = (float*)d_out;
    float* losso = pred + (size_t)BB * TT * DD;

    char* ws = (char*)d_ws;
    h4*       xwf    = (h4*)(ws + 0);                  // 268435456
    h4*       BhhV   = (h4*)(ws + 268435456);          //    262144
    h4*       BhhL   = (h4*)(ws + 268697600);          //    131072
    h4*       BhhS   = (h4*)(ws + 268828672);          //    131072
    _Float16* Bih    = (_Float16*)(ws + 268959744);    //    327680
    float*    pooled = (float*)(ws + 269287424);       //    524288
    float*    y0ws   = (float*)(ws + 269811712);       //    131072
    h4*       A1f    = (h4*)(ws + 269942784);          //     32768
    h4*       A2f    = (h4*)(ws + 269975552);          //     32768

    prep_kernel<<<448, 256, 0, stream>>>(W_hh, W_ih, Wd1, Wd2, BhhV, BhhL, BhhS, Bih, A1f, A2f);
    xw_kernel<<<2048, 256, 0, stream>>>(x, Bih, b_ih, b_hh, xwf);
    lstm_kernel<<<32, 512, 0, stream>>>((const h8*)BhhV, (const h8*)BhhL, (const h8*)BhhS,
                                        xwf, lengths, pooled);
    head_kernel<<<BB, 256, 0, stream>>>(pooled, Wp1, bp1, Wp2, bp2, y0ws);
    ode_kernel<<<32, 64, 0, stream>>>(y0ws, (const h8*)A1f, bd1, (const h8*)A2f, bd2,
                                      ltime, lfeat, lmask, pred, losso);
}

// Round 9
// 3456.321 us; speedup vs baseline: 1.0119x; 1.0119x over previous
//
#include <hip/hip_runtime.h>
#include <hip/hip_bf16.h>

#define BB 512
#define SS 256
#define HH 256
#define DD 64
#define TT 50
#define GG 1024   // 4*H
#define INW 129

typedef _Float16 h4 __attribute__((ext_vector_type(4)));
typedef _Float16 h8 __attribute__((ext_vector_type(8)));
typedef __fp16 hf2 __attribute__((ext_vector_type(2)));   // builtin-facing f16 pair
typedef float f32x4 __attribute__((ext_vector_type(4)));
typedef unsigned int u32;

__device__ inline float sigf(float x) { return 1.f / (1.f + __expf(-x)); }
__device__ inline float tanhf_(float x) { return 1.f - 2.f / (__expf(2.f * x) + 1.f); }

__device__ inline u32 pkrtz(float a, float b) {
    hf2 h = __builtin_amdgcn_cvt_pkrtz(a, b);
    return __builtin_bit_cast(u32, h);
}

// ============ prep ============
// Bhh (16-wave LSTM layout): slot s=(w*4+g)*8+ks (w<16, g<4, ks<8):
//   value(l,e) = W_hh[n][k], n = g*256 + 16w + (l&15), k = 32ks + 8(l>>4) + e
// Bih: validated layout. A1f/A2f: validated ODE A-fragment layouts.
__global__ __launch_bounds__(256) void prep_kernel(
    const float* __restrict__ W_hh, const float* __restrict__ W_ih,
    const float* __restrict__ Wd1, const float* __restrict__ Wd2,
    h4* __restrict__ Bhh4, _Float16* __restrict__ Bih,
    h4* __restrict__ A1f4, h4* __restrict__ A2f4)
{
    int idx = blockIdx.x * 256 + threadIdx.x;
    if (idx < 65536) {
        int eh = idx & 1;
        int l = (idx >> 1) & 63;
        int s = idx >> 7;              // [0,512) = (w*4+g)*8 + ks
        int ks = s & 7;
        int gw = s >> 3;               // w*4+g
        int w = gw >> 2, g = gw & 3;
        int n = g * 256 + 16 * w + (l & 15);
        int k = 32 * ks + 8 * (l >> 4) + 4 * eh;
        float4 v = *(const float4*)(W_hh + (size_t)n * HH + k);
        h4 o; o[0] = (_Float16)v.x; o[1] = (_Float16)v.y; o[2] = (_Float16)v.z; o[3] = (_Float16)v.w;
        Bhh4[idx] = o;
    } else if (idx < 106496) {
        int fj = idx - 65536;
        int eh = fj & 1;
        int l = (fj >> 1) & 63;
        int si = fj >> 7;              // [0,320) = ntile*5 + ks
        int ks = si % 5;
        int ntile = si / 5;
        int n = ntile * 16 + (l & 15);
        int k = 32 * ks + 8 * (l >> 4) + 4 * eh;
        h4 o;
#pragma unroll
        for (int i = 0; i < 4; i++) {
            int kk = k + i;
            o[i] = (_Float16)((kk < INW) ? W_ih[(size_t)n * INW + kk] : 0.f);
        }
        *(h4*)(Bih + (size_t)fj * 4) = o;
    } else if (idx < 110592) {
        int fj = idx - 106496;         // A1f
        int eh = fj & 1;
        int l = (fj >> 1) & 63;
        int slot = fj >> 7;            // t*2+ks
        int ks = slot & 1, t = slot >> 1;
        int row = 16 * t + (l & 15);
        int k = 32 * ks + 8 * (l >> 4) + 4 * eh;
        h4 o;
#pragma unroll
        for (int i = 0; i < 4; i++) o[i] = (_Float16)Wd1[(size_t)row * DD + k + i];
        A1f4[fj] = o;
    } else if (idx < 114688) {
        int fj = idx - 110592;         // A2f
        int eh = fj & 1;
        int l = (fj >> 1) & 63;
        int slot = fj >> 7;            // t2*8+ks
        int ks = slot & 7, t2 = slot >> 3;
        int row = 16 * t2 + (l & 15);
        int k = 32 * ks + 8 * (l >> 4) + 4 * eh;
        h4 o;
#pragma unroll
        for (int i = 0; i < 4; i++) o[i] = (_Float16)Wd2[(size_t)row * HH + k + i];
        A2f4[fj] = o;
    }
}

// ============ xw GEMM (MFMA): validated; slot remapped for 16-wave LSTM ============
__global__ __launch_bounds__(256) void xw_kernel(
    const float* __restrict__ x, const _Float16* __restrict__ Bih,
    const float* __restrict__ b_ih, const float* __restrict__ b_hh,
    h4* __restrict__ xwf)
{
    __shared__ __align__(16) _Float16 ash[4][5][64][8];   // 20 KB, A-frag layout
    int tid = threadIdx.x;
    int w4 = tid >> 6, l = tid & 63;
    int bx = blockIdx.x;
    int t = bx >> 3, Bb = bx & 7;           // 64 batch-rows: b = Bb*64 + rr

    for (int i = tid; i < 64 * 160; i += 256) {
        int rr = i / 160, kk = i % 160;
        float v = (kk < INW) ? x[((size_t)(Bb * 64 + rr) * SS + t) * INW + kk] : 0.f;
        ash[rr >> 4][kk >> 5][(((kk & 31) >> 3) << 4) + (rr & 15)][kk & 7] = (_Float16)v;
    }
    __syncthreads();

    h8 A[4][5];
#pragma unroll
    for (int ms = 0; ms < 4; ms++)
#pragma unroll
        for (int ks = 0; ks < 5; ks++)
            A[ms][ks] = *(h8*)&ash[ms][ks][l][0];

    const h8* Bih8 = (const h8*)Bih;
    for (int nt16 = 0; nt16 < 16; nt16++) {
        int ntile = w4 * 16 + nt16;
        h8 Bv[5];
#pragma unroll
        for (int ks = 0; ks < 5; ks++) Bv[ks] = Bih8[(ntile * 5 + ks) * 64 + l];
        int nb = ntile * 16 + (l & 15);
        float bias = b_ih[nb] + b_hh[nb];
        f32x4 acc[4];
#pragma unroll
        for (int ms = 0; ms < 4; ms++) acc[ms] = (f32x4){0.f, 0.f, 0.f, 0.f};
#pragma unroll
        for (int ks = 0; ks < 5; ks++)
#pragma unroll
            for (int ms = 0; ms < 4; ms++)
                acc[ms] = __builtin_amdgcn_mfma_f32_16x16x32_f16(A[ms][ks], Bv[ks], acc[ms], 0, 0, 0);
        // slot for 16-wave LSTM: w = ntile&15 (j>>4), g = ntile>>4 -> slot = w*4+g
        int slot = (ntile & 15) * 4 + (ntile >> 4);
#pragma unroll
        for (int ms = 0; ms < 4; ms++) {
            int bg = Bb * 4 + ms;
            h4 o;
#pragma unroll
            for (int r = 0; r < 4; r++) o[r] = (_Float16)(acc[ms][r] + bias);
            xwf[(((size_t)bg * SS + t) * 64 + slot) * 64 + l] = o;
        }
    }
}

// ============ LSTM v5: 32 blocks x 1024 thr (16 waves, 4/SIMD) ============
// Wave w owns j-cols [16w,16w+16) x 4 gates. ALL W_hh in registers (64/wave, AGPR-backed).
// LDS = 16 KB hbuf only. 4 waves/SIMD = 2x the latency hiding of the 512-thr version.
__global__ __launch_bounds__(1024, 4) void lstm_kernel(
    const h8* __restrict__ Bhh, const h4* __restrict__ xwf,
    const int* __restrict__ lengths, float* __restrict__ pooled)
{
    __shared__ __align__(16) _Float16 hbuf[2][8][64][8];  // 16 KB double-buffered A-frag h
    int tid = threadIdx.x;
    int w = tid >> 6, l = tid & 63;
    int q = l >> 4, b0 = l & 15;
    int bg = blockIdx.x;

    // weights: 4 gates x 8 ks = 32 h8 = 64 regs
    h8 Wv[4][8];
#pragma unroll
    for (int g = 0; g < 4; g++)
#pragma unroll
        for (int ks = 0; ks < 8; ks++)
            Wv[g][ks] = Bhh[((w * 4 + g) * 8 + ks) * 64 + l];

    int len_[4];
    float c_[4], pa[4];
#pragma unroll
    for (int r = 0; r < 4; r++) {
        len_[r] = lengths[bg * 16 + 4 * q + r];
        c_[r] = 0.f; pa[r] = 0.f;
    }

    // zero h buffers: 16 KB = 1024 uint4, exactly 1 per thread
    ((uint4*)hbuf)[tid] = make_uint4(0, 0, 0, 0);
    __syncthreads();

    int cur = 0;
    for (int t = 0; t < SS; t++) {
        // gate pre-activations (C-frag layout, 8B/lane coalesced), issued early
        const h4* xp = xwf + (((size_t)bg * SS + t) * 64 + w * 4) * 64 + l;
        h4 xv[4];
#pragma unroll
        for (int g = 0; g < 4; g++) xv[g] = xp[g * 64];

        f32x4 acc[4];
#pragma unroll
        for (int g = 0; g < 4; g++) acc[g] = (f32x4){0.f, 0.f, 0.f, 0.f};
#pragma unroll
        for (int ks = 0; ks < 8; ks++) {
            h8 A = *(const h8*)&hbuf[cur][ks][l][0];
#pragma unroll
            for (int g = 0; g < 4; g++)
                acc[g] = __builtin_amdgcn_mfma_f32_16x16x32_f16(A, Wv[g][ks], acc[g], 0, 0, 0);
        }
        // gates + h update (4 batches/lane)
#pragma unroll
        for (int r = 0; r < 4; r++) {
            float gi = acc[0][r] + (float)xv[0][r];
            float gf = acc[1][r] + (float)xv[1][r];
            float gg = acc[2][r] + (float)xv[2][r];
            float go = acc[3][r] + (float)xv[3][r];
            float cc = sigf(gf) * c_[r] + sigf(gi) * tanhf_(gg);
            c_[r] = cc;
            float hh = sigf(go) * tanhf_(cc);
            if (t < len_[r]) pa[r] += hh;
            int b = 4 * q + r;
            int j = 16 * w + b0;
            hbuf[cur ^ 1][j >> 5][(((j & 31) >> 3) << 4) + b][j & 7] = (_Float16)hh;
        }
        __syncthreads();
        cur ^= 1;
    }

#pragma unroll
    for (int r = 0; r < 4; r++) {
        int b = 4 * q + r;
        int j = 16 * w + b0;
        pooled[(size_t)(bg * 16 + b) * HH + j] = pa[r] / (float)len_[r];
    }
}

// ============ head: unchanged ============
__global__ __launch_bounds__(256) void head_kernel(
    const float* __restrict__ pooled, const float* __restrict__ Wp1,
    const float* __restrict__ bp1, const float* __restrict__ Wp2,
    const float* __restrict__ bp2, float* __restrict__ y0ws)
{
    __shared__ __align__(16) float psh[HH];
    __shared__ __align__(16) float rsh[HH];
    int tid = threadIdx.x, b = blockIdx.x;
    psh[tid] = pooled[(size_t)b * HH + tid];
    __syncthreads();
    float a = bp1[tid];
    const float* wr = Wp1 + (size_t)tid * HH;
#pragma unroll 8
    for (int k = 0; k < HH; k += 4) {
        float4 w = *(const float4*)(wr + k);
        a += psh[k] * w.x + psh[k + 1] * w.y + psh[k + 2] * w.z + psh[k + 3] * w.w;
    }
    rsh[tid] = fmaxf(a, 0.f);
    __syncthreads();
    if (tid < DD) {
        float acc = bp2[tid];
        const float* w2 = Wp2 + (size_t)tid * HH;
#pragma unroll 8
        for (int h = 0; h < HH; h += 4) {
            float4 w = *(const float4*)(w2 + h);
            acc += rsh[h] * w.x + rsh[h + 1] * w.y + rsh[h + 2] * w.z + rsh[h + 3] * w.w;
        }
        y0ws[(size_t)b * DD + tid] = acc;
    }
}

// ============ ODE v6: best-measured v3 structure (4 waves, 16 batches, 32 blocks)
//              + balanced padded strides (no XOR) + bias-seeded MFMA C ============
__global__ __launch_bounds__(256) void ode_kernel(
    const float* __restrict__ y0ws, const h8* __restrict__ A1f,
    const float* __restrict__ bd1, const h8* __restrict__ A2f,
    const float* __restrict__ bd2, const float* __restrict__ ltime,
    const float* __restrict__ lfeat, const float* __restrict__ lmask,
    float* __restrict__ pred, float* __restrict__ losso)
{
    __shared__ __align__(16) _Float16 hX[16 * 264];   // row stride 264 halfs (bank-balanced)
    __shared__ __align__(16) _Float16 kX[16 * 80];    // row stride 80
    int tid = threadIdx.x;
    int wv = tid >> 6, l = tid & 63;
    int q = l >> 4, bb = l & 15;
    int b = blockIdx.x * 16 + bb;

    // weights as A-fragments, resident in regs (wave wv's row-tiles)
    h8 A1[4][2];
#pragma unroll
    for (int tt = 0; tt < 4; tt++)
#pragma unroll
        for (int ks = 0; ks < 2; ks++)
            A1[tt][ks] = A1f[((4 * wv + tt) * 2 + ks) * 64 + l];
    h8 A2[8];
#pragma unroll
    for (int ks = 0; ks < 8; ks++) A2[ks] = A2f[(wv * 8 + ks) * 64 + l];

    // bias as C-seeds
    f32x4 BD1[4];
#pragma unroll
    for (int tt = 0; tt < 4; tt++)
#pragma unroll
        for (int r = 0; r < 4; r++) BD1[tt][r] = bd1[16 * (4 * wv + tt) + 4 * q + r];
    f32x4 BD2;
#pragma unroll
    for (int r = 0; r < 4; r++) BD2[r] = bd2[16 * wv + 4 * q + r];

    float y[16], kp[16], ksum[16];
#pragma unroll
    for (int ks2 = 0; ks2 < 2; ks2++)
#pragma unroll
        for (int e = 0; e < 8; e++) {
            y[ks2 * 8 + e] = y0ws[(size_t)b * DD + 32 * ks2 + 8 * q + e];
            kp[ks2 * 8 + e] = 0.f;
        }

    if (wv == 0) {   // pred/loss at ti=0
#pragma unroll
        for (int ks2 = 0; ks2 < 2; ks2++) {
            size_t idx = ((size_t)b * TT + 0) * DD + 32 * ks2 + 8 * q;
#pragma unroll
            for (int h4i = 0; h4i < 2; h4i++) {
                float4 p;
                p.x = y[ks2 * 8 + 4 * h4i + 0]; p.y = y[ks2 * 8 + 4 * h4i + 1];
                p.z = y[ks2 * 8 + 4 * h4i + 2]; p.w = y[ks2 * 8 + 4 * h4i + 3];
                *(float4*)&pred[idx + 4 * h4i] = p;
                float4 lf = *(const float4*)&lfeat[idx + 4 * h4i];
                float4 lm = *(const float4*)&lmask[idx + 4 * h4i];
                float4 lo;
                lo.x = (p.x - lf.x) * (p.x - lf.x) * (1.f - lm.x);
                lo.y = (p.y - lf.y) * (p.y - lf.y) * (1.f - lm.y);
                lo.z = (p.z - lf.z) * (p.z - lf.z) * (1.f - lm.z);
                lo.w = (p.w - lf.w) * (p.w - lf.w) * (1.f - lm.w);
                *(float4*)&losso[idx + 4 * h4i] = lo;
            }
        }
    }

    for (int iv = 0; iv < TT - 1; iv++) {
        float t0 = ltime[(size_t)b * TT + iv], t1 = ltime[(size_t)b * TT + iv + 1];
        float dt = (t1 - t0) * 0.125f;
        for (int ss = 0; ss < 8; ss++) {
#pragma unroll
            for (int i = 0; i < 16; i++) ksum[i] = 0.f;
            const float AE[4] = {0.f, 0.5f, 0.5f, 1.f};
            const float WE[4] = {1.f, 2.f, 2.f, 1.f};
#pragma unroll
            for (int e = 0; e < 4; e++) {
                float adt = AE[e] * dt;
                // B1 = pack(y + adt*kp), lane-local
                h8 B1[2];
#pragma unroll
                for (int ks2 = 0; ks2 < 2; ks2++) {
                    uint4 u;
                    u.x = pkrtz(y[ks2 * 8 + 0] + adt * kp[ks2 * 8 + 0], y[ks2 * 8 + 1] + adt * kp[ks2 * 8 + 1]);
                    u.y = pkrtz(y[ks2 * 8 + 2] + adt * kp[ks2 * 8 + 2], y[ks2 * 8 + 3] + adt * kp[ks2 * 8 + 3]);
                    u.z = pkrtz(y[ks2 * 8 + 4] + adt * kp[ks2 * 8 + 4], y[ks2 * 8 + 5] + adt * kp[ks2 * 8 + 5]);
                    u.w = pkrtz(y[ks2 * 8 + 6] + adt * kp[ks2 * 8 + 6], y[ks2 * 8 + 7] + adt * kp[ks2 * 8 + 7]);
                    B1[ks2] = __builtin_bit_cast(h8, u);
                }
                // GEMV1: 4 tiles x 2 ks, bias-seeded
                f32x4 C1[4];
#pragma unroll
                for (int tt = 0; tt < 4; tt++) C1[tt] = BD1[tt];
#pragma unroll
                for (int ks2 = 0; ks2 < 2; ks2++)
#pragma unroll
                    for (int tt = 0; tt < 4; tt++)
                        C1[tt] = __builtin_amdgcn_mfma_f32_16x16x32_f16(A1[tt][ks2], B1[ks2], C1[tt], 0, 0, 0);
                // relu + pack + store hX
#pragma unroll
                for (int tt = 0; tt < 4; tt++) {
                    u32 p0 = pkrtz(fmaxf(C1[tt][0], 0.f), fmaxf(C1[tt][1], 0.f));
                    u32 p1 = pkrtz(fmaxf(C1[tt][2], 0.f), fmaxf(C1[tt][3], 0.f));
                    *(uint2*)&hX[bb * 264 + 16 * (4 * wv + tt) + 4 * q] = make_uint2(p0, p1);
                }
                __syncthreads();
                // GEMV2: 1 tile x 8 ks, 2 chains, bias-seeded
                f32x4 Ca = BD2, Cb = (f32x4){0.f, 0.f, 0.f, 0.f};
#pragma unroll
                for (int ksi = 0; ksi < 8; ksi += 2) {
                    h8 B2a = *(const h8*)&hX[bb * 264 + 32 * ksi + 8 * q];
                    h8 B2b = *(const h8*)&hX[bb * 264 + 32 * (ksi + 1) + 8 * q];
                    Ca = __builtin_amdgcn_mfma_f32_16x16x32_f16(A2[ksi], B2a, Ca, 0, 0, 0);
                    Cb = __builtin_amdgcn_mfma_f32_16x16x32_f16(A2[ksi + 1], B2b, Cb, 0, 0, 0);
                }
                {
                    u32 p0 = pkrtz(Ca[0] + Cb[0], Ca[1] + Cb[1]);
                    u32 p1 = pkrtz(Ca[2] + Cb[2], Ca[3] + Cb[3]);
                    *(uint2*)&kX[bb * 80 + 16 * wv + 4 * q] = make_uint2(p0, p1);
                }
                __syncthreads();
                // read k back in B-frag layout; update kp/ksum
#pragma unroll
                for (int ks2 = 0; ks2 < 2; ks2++) {
                    h8 kf = *(const h8*)&kX[bb * 80 + 32 * ks2 + 8 * q];
#pragma unroll
                    for (int e2 = 0; e2 < 8; e2++) {
                        float kv = (float)kf[e2];
                        kp[ks2 * 8 + e2] = kv;
                        ksum[ks2 * 8 + e2] += WE[e] * kv;
                    }
                }
            }
#pragma unroll
            for (int i = 0; i < 16; i++) y[i] += dt * (1.f / 6.f) * ksum[i];
        }
        if (wv == 0) {   // pred/loss at ti=iv+1
#pragma unroll
            for (int ks2 = 0; ks2 < 2; ks2++) {
                size_t idx = ((size_t)b * TT + iv + 1) * DD + 32 * ks2 + 8 * q;
#pragma unroll
                for (int h4i = 0; h4i < 2; h4i++) {
                    float4 p;
                    p.x = y[ks2 * 8 + 4 * h4i + 0]; p.y = y[ks2 * 8 + 4 * h4i + 1];
                    p.z = y[ks2 * 8 + 4 * h4i + 2]; p.w = y[ks2 * 8 + 4 * h4i + 3];
                    *(float4*)&pred[idx + 4 * h4i] = p;
                    float4 lf = *(const float4*)&lfeat[idx + 4 * h4i];
                    float4 lm = *(const float4*)&lmask[idx + 4 * h4i];
                    float4 lo;
                    lo.x = (p.x - lf.x) * (p.x - lf.x) * (1.f - lm.x);
                    lo.y = (p.y - lf.y) * (p.y - lf.y) * (1.f - lm.y);
                    lo.z = (p.z - lf.z) * (p.z - lf.z) * (1.f - lm.z);
                    lo.w = (p.w - lf.w) * (p.w - lf.w) * (1.f - lm.w);
                    *(float4*)&losso[idx + 4 * h4i] = lo;
                }
            }
        }
    }
}

extern "C" void kernel_launch(void* const* d_in, const int* in_sizes, int n_in,
                              void* d_out, int out_size, void* d_ws, size_t ws_size,
                              hipStream_t stream)
{
    const float* x      = (const float*)d_in[0];
    const int* lengths  = (const int*)d_in[1];
    const float* lfeat  = (const float*)d_in[2];
    const float* ltime  = (const float*)d_in[3];
    const float* lmask  = (const float*)d_in[4];
    const float* W_ih   = (const float*)d_in[5];
    const float* W_hh   = (const float*)d_in[6];
    const float* b_ih   = (const float*)d_in[7];
    const float* b_hh   = (const float*)d_in[8];
    const float* Wp1    = (const float*)d_in[9];
    const float* bp1    = (const float*)d_in[10];
    const float* Wp2    = (const float*)d_in[11];
    const float* bp2    = (const float*)d_in[12];
    const float* Wd1    = (const float*)d_in[13];
    const float* bd1    = (const float*)d_in[14];
    const float* Wd2    = (const float*)d_in[15];
    const float* bd2    = (const float*)d_in[16];

    float* pred  = (float*)d_out;
    float* losso = pred + (size_t)BB * TT * DD;

    char* ws = (char*)d_ws;
    h4*       xwf    = (h4*)(ws + 0);                  // 268435456
    h4*       Bhh    = (h4*)(ws + 268435456);          //    524288
    _Float16* Bih    = (_Float16*)(ws + 268959744);    //    327680
    float*    pooled = (float*)(ws + 269287424);       //    524288
    float*    y0ws   = (float*)(ws + 269811712);       //    131072
    h4*       A1f    = (h4*)(ws + 269942784);          //     32768
    h4*       A2f    = (h4*)(ws + 269975552);          //     32768

    prep_kernel<<<448, 256, 0, stream>>>(W_hh, W_ih, Wd1, Wd2, Bhh, Bih, A1f, A2f);
    xw_kernel<<<2048, 256, 0, stream>>>(x, Bih, b_ih, b_hh, xwf);
    lstm_kernel<<<32, 1024, 0, stream>>>((const h8*)Bhh, xwf, lengths, pooled);
    head_kernel<<<BB, 256, 0, stream>>>(pooled, Wp1, bp1, Wp2, bp2, y0ws);
    ode_kernel<<<32, 256, 0, stream>>>(y0ws, (const h8*)A1f, bd1, (const h8*)A2f, bd2,
                                       ltime, lfeat, lmask, pred, losso);
}

// Round 10
// 2581.552 us; speedup vs baseline: 1.3548x; 1.3389x over previous
//
#include <hip/hip_runtime.h>
#include <hip/hip_bf16.h>

#define BB 512
#define SS 256
#define HH 256
#define DD 64
#define TT 50
#define GG 1024   // 4*H
#define INW 129

typedef _Float16 h4 __attribute__((ext_vector_type(4)));
typedef _Float16 h8 __attribute__((ext_vector_type(8)));
typedef __fp16 hf2 __attribute__((ext_vector_type(2)));   // builtin-facing f16 pair
typedef float f32x4 __attribute__((ext_vector_type(4)));
typedef unsigned int u32;

__device__ inline float sigf(float x) { return 1.f / (1.f + __expf(-x)); }
__device__ inline float tanhf_(float x) { return 1.f - 2.f / (__expf(2.f * x) + 1.f); }

__device__ inline u32 pkrtz(float a, float b) {
    hf2 h = __builtin_amdgcn_cvt_pkrtz(a, b);
    return __builtin_bit_cast(u32, h);
}

// ============ prep ============
// 8-wave LSTM layout (r5-validated), weight split now 3/2/3:
//   slot s = jt*4+g, wave w: value(l,e) = W_hh[n][k], n = g*256+w*32+jt*16+(l&15),
//   k = 32ks+8(l>>4)+e.  ks0-2 -> BhhV (AGPR), ks4-5 -> BhhL (LDS), ks6,7,3 -> BhhS (L2 stream)
// Bih / A1f / A2f: validated layouts, unchanged.
__global__ __launch_bounds__(256) void prep_kernel(
    const float* __restrict__ W_hh, const float* __restrict__ W_ih,
    const float* __restrict__ Wd1, const float* __restrict__ Wd2,
    h4* __restrict__ BhhV4, h4* __restrict__ BhhL4, h4* __restrict__ BhhS4,
    _Float16* __restrict__ Bih, h4* __restrict__ A1f4, h4* __restrict__ A2f4)
{
    int idx = blockIdx.x * 256 + threadIdx.x;
    if (idx < 65536) {
        int eh = idx & 1;
        int l = (idx >> 1) & 63;
        int ks = (idx >> 7) & 7;
        int s = (idx >> 10) & 7;
        int w = (idx >> 13) & 7;
        int g = s & 3, jt = s >> 2;
        int n = g * 256 + w * 32 + jt * 16 + (l & 15);
        int k = 32 * ks + 8 * (l >> 4) + 4 * eh;
        float4 v = *(const float4*)(W_hh + (size_t)n * HH + k);
        h4 o; o[0] = (_Float16)v.x; o[1] = (_Float16)v.y; o[2] = (_Float16)v.z; o[3] = (_Float16)v.w;
        if (ks < 3)
            BhhV4[(((w * 8 + s) * 3 + ks) * 64 + l) * 2 + eh] = o;
        else if (ks == 4 || ks == 5)
            BhhL4[(((w * 8 + s) * 2 + (ks - 4)) * 64 + l) * 2 + eh] = o;
        else {
            int sub = (ks == 6) ? 0 : (ks == 7) ? 1 : 2;   // ks3 -> sub 2
            BhhS4[(((w * 8 + s) * 3 + sub) * 64 + l) * 2 + eh] = o;
        }
    } else if (idx < 106496) {
        int fj = idx - 65536;
        int eh = fj & 1;
        int l = (fj >> 1) & 63;
        int si = fj >> 7;              // [0,320) = ntile*5 + ks
        int ks = si % 5;
        int ntile = si / 5;
        int n = ntile * 16 + (l & 15);
        int k = 32 * ks + 8 * (l >> 4) + 4 * eh;
        h4 o;
#pragma unroll
        for (int i = 0; i < 4; i++) {
            int kk = k + i;
            o[i] = (_Float16)((kk < INW) ? W_ih[(size_t)n * INW + kk] : 0.f);
        }
        *(h4*)(Bih + (size_t)fj * 4) = o;
    } else if (idx < 110592) {
        int fj = idx - 106496;         // A1f
        int eh = fj & 1;
        int l = (fj >> 1) & 63;
        int slot = fj >> 7;            // t*2+ks
        int ks = slot & 1, t = slot >> 1;
        int row = 16 * t + (l & 15);
        int k = 32 * ks + 8 * (l >> 4) + 4 * eh;
        h4 o;
#pragma unroll
        for (int i = 0; i < 4; i++) o[i] = (_Float16)Wd1[(size_t)row * DD + k + i];
        A1f4[fj] = o;
    } else if (idx < 114688) {
        int fj = idx - 110592;         // A2f
        int eh = fj & 1;
        int l = (fj >> 1) & 63;
        int slot = fj >> 7;            // t2*8+ks
        int ks = slot & 7, t2 = slot >> 3;
        int row = 16 * t2 + (l & 15);
        int k = 32 * ks + 8 * (l >> 4) + 4 * eh;
        h4 o;
#pragma unroll
        for (int i = 0; i < 4; i++) o[i] = (_Float16)Wd2[(size_t)row * HH + k + i];
        A2f4[fj] = o;
    }
}

// ============ xw GEMM (MFMA): validated r5 version (8-wave slot mapping) ============
__global__ __launch_bounds__(256) void xw_kernel(
    const float* __restrict__ x, const _Float16* __restrict__ Bih,
    const float* __restrict__ b_ih, const float* __restrict__ b_hh,
    h4* __restrict__ xwf)
{
    __shared__ __align__(16) _Float16 ash[4][5][64][8];   // 20 KB, A-frag layout
    int tid = threadIdx.x;
    int w4 = tid >> 6, l = tid & 63;
    int bx = blockIdx.x;
    int t = bx >> 3, Bb = bx & 7;           // 64 batch-rows: b = Bb*64 + rr

    for (int i = tid; i < 64 * 160; i += 256) {
        int rr = i / 160, kk = i % 160;
        float v = (kk < INW) ? x[((size_t)(Bb * 64 + rr) * SS + t) * INW + kk] : 0.f;
        ash[rr >> 4][kk >> 5][(((kk & 31) >> 3) << 4) + (rr & 15)][kk & 7] = (_Float16)v;
    }
    __syncthreads();

    h8 A[4][5];
#pragma unroll
    for (int ms = 0; ms < 4; ms++)
#pragma unroll
        for (int ks = 0; ks < 5; ks++)
            A[ms][ks] = *(h8*)&ash[ms][ks][l][0];

    const h8* Bih8 = (const h8*)Bih;
    for (int nt16 = 0; nt16 < 16; nt16++) {
        int ntile = w4 * 16 + nt16;
        h8 Bv[5];
#pragma unroll
        for (int ks = 0; ks < 5; ks++) Bv[ks] = Bih8[(ntile * 5 + ks) * 64 + l];
        int nb = ntile * 16 + (l & 15);
        float bias = b_ih[nb] + b_hh[nb];
        f32x4 acc[4];
#pragma unroll
        for (int ms = 0; ms < 4; ms++) acc[ms] = (f32x4){0.f, 0.f, 0.f, 0.f};
#pragma unroll
        for (int ks = 0; ks < 5; ks++)
#pragma unroll
            for (int ms = 0; ms < 4; ms++)
                acc[ms] = __builtin_amdgcn_mfma_f32_16x16x32_f16(A[ms][ks], Bv[ks], acc[ms], 0, 0, 0);
        // slot for 8-wave LSTM: w = (ntile&15)>>1, jt = ntile&1, g = ntile>>4
        int slot = ((ntile & 15) >> 1) * 8 + (ntile & 1) * 4 + (ntile >> 4);
#pragma unroll
        for (int ms = 0; ms < 4; ms++) {
            int bg = Bb * 4 + ms;
            h4 o;
#pragma unroll
            for (int r = 0; r < 4; r++) o[r] = (_Float16)(acc[ms][r] + bias);
            xwf[(((size_t)bg * SS + t) * 64 + slot) * 64 + l] = o;
        }
    }
}

// ============ LSTM v6: r5 structure + full-step xv prefetch (ks3 moved AGPR->stream) ============
// 32 blocks x 512 thr (8 waves, 2/SIMD, 256-reg budget). Register budget:
//   weights ks0-2 = 24 h8 = 96 AGPR; xc+xn prefetch = 32 VGPR; streams <= 32 in flight.
__global__ __launch_bounds__(512, 2) void lstm_kernel(
    const h8* __restrict__ BhhV, const h8* __restrict__ BhhL, const h8* __restrict__ BhhS,
    const h4* __restrict__ xwf, const int* __restrict__ lengths, float* __restrict__ pooled)
{
    __shared__ __align__(16) _Float16 Wlds[65536];        // 128 KB: ks4-5 weight fragments
    __shared__ __align__(16) _Float16 hbuf[2][8][64][8];  // 16 KB double-buffered A-frag h
    int tid = threadIdx.x;
    int w = tid >> 6, l = tid & 63;
    int bg = blockIdx.x;

    {   // copy ks4-5 weights into LDS (linear, 128 KB)
        const uint4* src = (const uint4*)BhhL;
        uint4* dst = (uint4*)Wlds;
#pragma unroll
        for (int i = 0; i < 16; i++) dst[i * 512 + tid] = src[i * 512 + tid];
    }

    // VGPR/AGPR-resident weights: 8 slots x ks0-2 = 96 regs
    h8 Wv[8][3];
#pragma unroll
    for (int s = 0; s < 8; s++)
#pragma unroll
        for (int ks = 0; ks < 3; ks++)
            Wv[s][ks] = BhhV[((w * 8 + s) * 3 + ks) * 64 + l];

    int len_[4];
    float c_[2][4], pa[2][4];
#pragma unroll
    for (int r = 0; r < 4; r++) {
        int b = 4 * (l >> 4) + r;
        len_[r] = lengths[bg * 16 + b];
#pragma unroll
        for (int jt = 0; jt < 2; jt++) { c_[jt][r] = 0.f; pa[jt][r] = 0.f; }
    }

    {   // zero h buffers (h0 = 0): 1024 uint4, 2 per thread
        uint4* hz = (uint4*)hbuf;
        hz[tid] = make_uint4(0, 0, 0, 0);
        hz[512 + tid] = make_uint4(0, 0, 0, 0);
    }
    __syncthreads();

    // preload xv for t=0
    h4 xc[8], xn[8];
    {
        const h4* p0 = xwf + (((size_t)bg * SS + 0) * 64 + w * 8) * 64 + l;
#pragma unroll
        for (int s = 0; s < 8; s++) xc[s] = p0[s * 64];
    }

    int cur = 0;
    for (int t = 0; t < SS; t++) {
        // prefetch xv for t+1: consumed a FULL STEP later (~10k cyc) -> HBM latency fully hidden
        int tn = (t + 1) & 255;
        const h4* pn = xwf + (((size_t)bg * SS + tn) * 64 + w * 8) * 64 + l;
#pragma unroll
        for (int s = 0; s < 8; s++) xn[s] = pn[s * 64];

        int zoff = 0;
        asm volatile("" : "+v"(zoff));            // block LICM on streamed weights
        const h8* bS = BhhS + zoff;
#pragma unroll
        for (int jt = 0; jt < 2; jt++) {
            // issue streamed ks6, ks7 (8 h8 in flight)
            h8 Ws6[4], Ws7[4], Ws3[4];
#pragma unroll
            for (int g = 0; g < 4; g++) {
                Ws6[g] = bS[((w * 8 + jt * 4 + g) * 3 + 0) * 64 + l];
                Ws7[g] = bS[((w * 8 + jt * 4 + g) * 3 + 1) * 64 + l];
            }
            f32x4 acc[4];
#pragma unroll
            for (int g = 0; g < 4; g++) acc[g] = (f32x4){0.f, 0.f, 0.f, 0.f};
            // ks 0-2 from resident regs
#pragma unroll
            for (int ks = 0; ks < 3; ks++) {
                h8 A = *(const h8*)&hbuf[cur][ks][l][0];
#pragma unroll
                for (int g = 0; g < 4; g++)
                    acc[g] = __builtin_amdgcn_mfma_f32_16x16x32_f16(A, Wv[jt * 4 + g][ks], acc[g], 0, 0, 0);
            }
            // ks 6 (stream landed during ks0-2)
            {
                h8 A = *(const h8*)&hbuf[cur][6][l][0];
#pragma unroll
                for (int g = 0; g < 4; g++)
                    acc[g] = __builtin_amdgcn_mfma_f32_16x16x32_f16(A, Ws6[g], acc[g], 0, 0, 0);
            }
            // issue streamed ks3 (lands during ks4-5/ks7)
#pragma unroll
            for (int g = 0; g < 4; g++) Ws3[g] = bS[((w * 8 + jt * 4 + g) * 3 + 2) * 64 + l];
            // ks 4-5 from LDS
#pragma unroll
            for (int ks = 4; ks < 6; ks++) {
                h8 A = *(const h8*)&hbuf[cur][ks][l][0];
#pragma unroll
                for (int g = 0; g < 4; g++) {
                    h8 Bw = *(const h8*)&Wlds[(((w * 8 + jt * 4 + g) * 2 + (ks - 4)) * 64 + l) * 8];
                    acc[g] = __builtin_amdgcn_mfma_f32_16x16x32_f16(A, Bw, acc[g], 0, 0, 0);
                }
            }
            // ks 7
            {
                h8 A = *(const h8*)&hbuf[cur][7][l][0];
#pragma unroll
                for (int g = 0; g < 4; g++)
                    acc[g] = __builtin_amdgcn_mfma_f32_16x16x32_f16(A, Ws7[g], acc[g], 0, 0, 0);
            }
            // ks 3 (stream landed)
            {
                h8 A = *(const h8*)&hbuf[cur][3][l][0];
#pragma unroll
                for (int g = 0; g < 4; g++)
                    acc[g] = __builtin_amdgcn_mfma_f32_16x16x32_f16(A, Ws3[g], acc[g], 0, 0, 0);
            }
            // gates + h update (xc prefetched a full step ago)
#pragma unroll
            for (int r = 0; r < 4; r++) {
                float gi = acc[0][r] + (float)xc[jt * 4 + 0][r];
                float gf = acc[1][r] + (float)xc[jt * 4 + 1][r];
                float gg = acc[2][r] + (float)xc[jt * 4 + 2][r];
                float go = acc[3][r] + (float)xc[jt * 4 + 3][r];
                float cc = sigf(gf) * c_[jt][r] + sigf(gi) * tanhf_(gg);
                c_[jt][r] = cc;
                float hh = sigf(go) * tanhf_(cc);
                if (t < len_[r]) pa[jt][r] += hh;
                int b = 4 * (l >> 4) + r;
                int j = w * 32 + jt * 16 + (l & 15);
                hbuf[cur ^ 1][j >> 5][(((j & 31) >> 3) << 4) + b][j & 7] = (_Float16)hh;
            }
        }
        __syncthreads();
#pragma unroll
        for (int s = 0; s < 8; s++) xc[s] = xn[s];
        cur ^= 1;
    }

#pragma unroll
    for (int jt = 0; jt < 2; jt++)
#pragma unroll
        for (int r = 0; r < 4; r++) {
            int b = 4 * (l >> 4) + r;
            int j = w * 32 + jt * 16 + (l & 15);
            pooled[(size_t)(bg * 16 + b) * HH + j] = pa[jt][r] / (float)len_[r];
        }
}

// ============ head: unchanged ============
__global__ __launch_bounds__(256) void head_kernel(
    const float* __restrict__ pooled, const float* __restrict__ Wp1,
    const float* __restrict__ bp1, const float* __restrict__ Wp2,
    const float* __restrict__ bp2, float* __restrict__ y0ws)
{
    __shared__ __align__(16) float psh[HH];
    __shared__ __align__(16) float rsh[HH];
    int tid = threadIdx.x, b = blockIdx.x;
    psh[tid] = pooled[(size_t)b * HH + tid];
    __syncthreads();
    float a = bp1[tid];
    const float* wr = Wp1 + (size_t)tid * HH;
#pragma unroll 8
    for (int k = 0; k < HH; k += 4) {
        float4 w = *(const float4*)(wr + k);
        a += psh[k] * w.x + psh[k + 1] * w.y + psh[k + 2] * w.z + psh[k + 3] * w.w;
    }
    rsh[tid] = fmaxf(a, 0.f);
    __syncthreads();
    if (tid < DD) {
        float acc = bp2[tid];
        const float* w2 = Wp2 + (size_t)tid * HH;
#pragma unroll 8
        for (int h = 0; h < HH; h += 4) {
            float4 w = *(const float4*)(w2 + h);
            acc += rsh[h] * w.x + rsh[h + 1] * w.y + rsh[h + 2] * w.z + rsh[h + 3] * w.w;
        }
        y0ws[(size_t)b * DD + tid] = acc;
    }
}

// ============ ODE v6 (kept): 4 waves, 16 batches, 32 blocks; padded strides; bias-seeded C ====
__global__ __launch_bounds__(256) void ode_kernel(
    const float* __restrict__ y0ws, const h8* __restrict__ A1f,
    const float* __restrict__ bd1, const h8* __restrict__ A2f,
    const float* __restrict__ bd2, const float* __restrict__ ltime,
    const float* __restrict__ lfeat, const float* __restrict__ lmask,
    float* __restrict__ pred, float* __restrict__ losso)
{
    __shared__ __align__(16) _Float16 hX[16 * 264];   // row stride 264 halfs (bank-balanced)
    __shared__ __align__(16) _Float16 kX[16 * 80];    // row stride 80
    int tid = threadIdx.x;
    int wv = tid >> 6, l = tid & 63;
    int q = l >> 4, bb = l & 15;
    int b = blockIdx.x * 16 + bb;

    h8 A1[4][2];
#pragma unroll
    for (int tt = 0; tt < 4; tt++)
#pragma unroll
        for (int ks = 0; ks < 2; ks++)
            A1[tt][ks] = A1f[((4 * wv + tt) * 2 + ks) * 64 + l];
    h8 A2[8];
#pragma unroll
    for (int ks = 0; ks < 8; ks++) A2[ks] = A2f[(wv * 8 + ks) * 64 + l];

    f32x4 BD1[4];
#pragma unroll
    for (int tt = 0; tt < 4; tt++)
#pragma unroll
        for (int r = 0; r < 4; r++) BD1[tt][r] = bd1[16 * (4 * wv + tt) + 4 * q + r];
    f32x4 BD2;
#pragma unroll
    for (int r = 0; r < 4; r++) BD2[r] = bd2[16 * wv + 4 * q + r];

    float y[16], kp[16], ksum[16];
#pragma unroll
    for (int ks2 = 0; ks2 < 2; ks2++)
#pragma unroll
        for (int e = 0; e < 8; e++) {
            y[ks2 * 8 + e] = y0ws[(size_t)b * DD + 32 * ks2 + 8 * q + e];
            kp[ks2 * 8 + e] = 0.f;
        }

    if (wv == 0) {   // pred/loss at ti=0
#pragma unroll
        for (int ks2 = 0; ks2 < 2; ks2++) {
            size_t idx = ((size_t)b * TT + 0) * DD + 32 * ks2 + 8 * q;
#pragma unroll
            for (int h4i = 0; h4i < 2; h4i++) {
                float4 p;
                p.x = y[ks2 * 8 + 4 * h4i + 0]; p.y = y[ks2 * 8 + 4 * h4i + 1];
                p.z = y[ks2 * 8 + 4 * h4i + 2]; p.w = y[ks2 * 8 + 4 * h4i + 3];
                *(float4*)&pred[idx + 4 * h4i] = p;
                float4 lf = *(const float4*)&lfeat[idx + 4 * h4i];
                float4 lm = *(const float4*)&lmask[idx + 4 * h4i];
                float4 lo;
                lo.x = (p.x - lf.x) * (p.x - lf.x) * (1.f - lm.x);
                lo.y = (p.y - lf.y) * (p.y - lf.y) * (1.f - lm.y);
                lo.z = (p.z - lf.z) * (p.z - lf.z) * (1.f - lm.z);
                lo.w = (p.w - lf.w) * (p.w - lf.w) * (1.f - lm.w);
                *(float4*)&losso[idx + 4 * h4i] = lo;
            }
        }
    }

    for (int iv = 0; iv < TT - 1; iv++) {
        float t0 = ltime[(size_t)b * TT + iv], t1 = ltime[(size_t)b * TT + iv + 1];
        float dt = (t1 - t0) * 0.125f;
        for (int ss = 0; ss < 8; ss++) {
#pragma unroll
            for (int i = 0; i < 16; i++) ksum[i] = 0.f;
            const float AE[4] = {0.f, 0.5f, 0.5f, 1.f};
            const float WE[4] = {1.f, 2.f, 2.f, 1.f};
#pragma unroll
            for (int e = 0; e < 4; e++) {
                float adt = AE[e] * dt;
                h8 B1[2];
#pragma unroll
                for (int ks2 = 0; ks2 < 2; ks2++) {
                    uint4 u;
                    u.x = pkrtz(y[ks2 * 8 + 0] + adt * kp[ks2 * 8 + 0], y[ks2 * 8 + 1] + adt * kp[ks2 * 8 + 1]);
                    u.y = pkrtz(y[ks2 * 8 + 2] + adt * kp[ks2 * 8 + 2], y[ks2 * 8 + 3] + adt * kp[ks2 * 8 + 3]);
                    u.z = pkrtz(y[ks2 * 8 + 4] + adt * kp[ks2 * 8 + 4], y[ks2 * 8 + 5] + adt * kp[ks2 * 8 + 5]);
                    u.w = pkrtz(y[ks2 * 8 + 6] + adt * kp[ks2 * 8 + 6], y[ks2 * 8 + 7] + adt * kp[ks2 * 8 + 7]);
                    B1[ks2] = __builtin_bit_cast(h8, u);
                }
                f32x4 C1[4];
#pragma unroll
                for (int tt = 0; tt < 4; tt++) C1[tt] = BD1[tt];
#pragma unroll
                for (int ks2 = 0; ks2 < 2; ks2++)
#pragma unroll
                    for (int tt = 0; tt < 4; tt++)
                        C1[tt] = __builtin_amdgcn_mfma_f32_16x16x32_f16(A1[tt][ks2], B1[ks2], C1[tt], 0, 0, 0);
#pragma unroll
                for (int tt = 0; tt < 4; tt++) {
                    u32 p0 = pkrtz(fmaxf(C1[tt][0], 0.f), fmaxf(C1[tt][1], 0.f));
                    u32 p1 = pkrtz(fmaxf(C1[tt][2], 0.f), fmaxf(C1[tt][3], 0.f));
                    *(uint2*)&hX[bb * 264 + 16 * (4 * wv + tt) + 4 * q] = make_uint2(p0, p1);
                }
                __syncthreads();
                f32x4 Ca = BD2, Cb = (f32x4){0.f, 0.f, 0.f, 0.f};
#pragma unroll
                for (int ksi = 0; ksi < 8; ksi += 2) {
                    h8 B2a = *(const h8*)&hX[bb * 264 + 32 * ksi + 8 * q];
                    h8 B2b = *(const h8*)&hX[bb * 264 + 32 * (ksi + 1) + 8 * q];
                    Ca = __builtin_amdgcn_mfma_f32_16x16x32_f16(A2[ksi], B2a, Ca, 0, 0, 0);
                    Cb = __builtin_amdgcn_mfma_f32_16x16x32_f16(A2[ksi + 1], B2b, Cb, 0, 0, 0);
                }
                {
                    u32 p0 = pkrtz(Ca[0] + Cb[0], Ca[1] + Cb[1]);
                    u32 p1 = pkrtz(Ca[2] + Cb[2], Ca[3] + Cb[3]);
                    *(uint2*)&kX[bb * 80 + 16 * wv + 4 * q] = make_uint2(p0, p1);
                }
                __syncthreads();
#pragma unroll
                for (int ks2 = 0; ks2 < 2; ks2++) {
                    h8 kf = *(const h8*)&kX[bb * 80 + 32 * ks2 + 8 * q];
#pragma unroll
                    for (int e2 = 0; e2 < 8; e2++) {
                        float kv = (float)kf[e2];
                        kp[ks2 * 8 + e2] = kv;
                        ksum[ks2 * 8 + e2] += WE[e] * kv;
                    }
                }
            }
#pragma unroll
            for (int i = 0; i < 16; i++) y[i] += dt * (1.f / 6.f) * ksum[i];
        }
        if (wv == 0) {   // pred/loss at ti=iv+1
#pragma unroll
            for (int ks2 = 0; ks2 < 2; ks2++) {
                size_t idx = ((size_t)b * TT + iv + 1) * DD + 32 * ks2 + 8 * q;
#pragma unroll
                for (int h4i = 0; h4i < 2; h4i++) {
                    float4 p;
                    p.x = y[ks2 * 8 + 4 * h4i + 0]; p.y = y[ks2 * 8 + 4 * h4i + 1];
                    p.z = y[ks2 * 8 + 4 * h4i + 2]; p.w = y[ks2 * 8 + 4 * h4i + 3];
                    *(float4*)&pred[idx + 4 * h4i] = p;
                    float4 lf = *(const float4*)&lfeat[idx + 4 * h4i];
                    float4 lm = *(const float4*)&lmask[idx + 4 * h4i];
                    float4 lo;
                    lo.x = (p.x - lf.x) * (p.x - lf.x) * (1.f - lm.x);
                    lo.y = (p.y - lf.y) * (p.y - lf.y) * (1.f - lm.y);
                    lo.z = (p.z - lf.z) * (p.z - lf.z) * (1.f - lm.z);
                    lo.w = (p.w - lf.w) * (p.w - lf.w) * (1.f - lm.w);
                    *(float4*)&losso[idx + 4 * h4i] = lo;
                }
            }
        }
    }
}

extern "C" void kernel_launch(void* const* d_in, const int* in_sizes, int n_in,
                              void* d_out, int out_size, void* d_ws, size_t ws_size,
                              hipStream_t stream)
{
    const float* x      = (const float*)d_in[0];
    const int* lengths  = (const int*)d_in[1];
    const float* lfeat  = (const float*)d_in[2];
    const float* ltime  = (const float*)d_in[3];
    const float* lmask  = (const float*)d_in[4];
    const float* W_ih   = (const float*)d_in[5];
    const float* W_hh   = (const float*)d_in[6];
    const float* b_ih   = (const float*)d_in[7];
    const float* b_hh   = (const float*)d_in[8];
    const float* Wp1    = (const float*)d_in[9];
    const float* bp1    = (const float*)d_in[10];
    const float* Wp2    = (const float*)d_in[11];
    const float* bp2    = (const float*)d_in[12];
    const float* Wd1    = (const float*)d_in[13];
    const float* bd1    = (const float*)d_in[14];
    const float* Wd2    = (const float*)d_in[15];
    const float* bd2    = (const float*)d_in[16];

    float* pred  = (float*)d_out;
    float* losso = pred + (size_t)BB * TT * DD;

    char* ws = (char*)d_ws;
    h4*       xwf    = (h4*)(ws + 0);                  // 268435456
    h4*       BhhV   = (h4*)(ws + 268435456);          //    196608 (3 ks)
    h4*       BhhL   = (h4*)(ws + 268632064);          //    131072 (2 ks)
    h4*       BhhS   = (h4*)(ws + 268763136);          //    196608 (3 ks: 6,7,3)
    _Float16* Bih    = (_Float16*)(ws + 268959744);    //    327680
    float*    pooled = (float*)(ws + 269287424);       //    524288
    float*    y0ws   = (float*)(ws + 269811712);       //    131072
    h4*       A1f    = (h4*)(ws + 269942784);          //     32768
    h4*       A2f    = (h4*)(ws + 269975552);          //     32768

    prep_kernel<<<448, 256, 0, stream>>>(W_hh, W_ih, Wd1, Wd2, BhhV, BhhL, BhhS, Bih, A1f, A2f);
    xw_kernel<<<2048, 256, 0, stream>>>(x, Bih, b_ih, b_hh, xwf);
    lstm_kernel<<<32, 512, 0, stream>>>((const h8*)BhhV, (const h8*)BhhL, (const h8*)BhhS,
                                        xwf, lengths, pooled);
    head_kernel<<<BB, 256, 0, stream>>>(pooled, Wp1, bp1, Wp2, bp2, y0ws);
    ode_kernel<<<32, 256, 0, stream>>>(y0ws, (const h8*)A1f, bd1, (const h8*)A2f, bd2,
                                       ltime, lfeat, lmask, pred, losso);
}